// Round 10
// baseline (152.200 us; speedup 1.0000x reference)
//
#include <hip/hip_runtime.h>

// rosa_4bit_layer: causal linear attention with per-head 4x4 state.
//   S_t = S_{t-1} + k_t v_t^T ;  o_t = q_t^T S_t ;  out = o * emb
// Shapes: x{q,k,v}: (B=4, T=4096, C=512) fp32, emb: (1,1,512) fp32.
// H = 128 heads, head_dim = 4 (contiguous 4-float groups in C).
//
// R9 post-mortem: spill fixed (WRITE back to 32 MB-class), 148 us total.
// Budget: fills/fixed ~80-85 us; kernels ~58-63 us vs ~35 us floor.
// k_out's olocal[8] holds ~100 VGPR -> 2 blocks/CU = 50% occupancy ->
// ~4 TB/s. R10: drop olocal, REPLAY k,v instead (the block's 128 KB of
// k,v was just fetched into its XCD L2 -> re-read is L2-hit, no HBM
// cost), q read exactly once. ~60 live VGPR -> __launch_bounds__(512,3)
// (cap ~84 under the observed CUDA-style blocks/CU semantics) -> 3
// blocks/CU = 24 waves/CU, LDS 3x32 KiB = 96 KiB/CU <= 160 ok.
// Layout (R8, vindicated): thread = (head h, t-subrange) owning the full
// 4x4 state; every k4/v4/q4 load and o4 store is 1 KB contiguous/wave.
// 3 dispatches: partial -> parallel scan -> out.

constexpr int B   = 4;
constexpr int T   = 4096;
constexpr int C   = 512;
constexpr int H   = 128;        // heads
constexpr int NC  = 128;        // chunks per sequence
constexpr int CT  = T / NC;     // 32 timesteps per chunk
constexpr int SG  = 4;          // t-subchunks per block
constexpr int TSS = CT / SG;    // 8 timesteps per thread
constexpr int NBLK = B * NC;    // 512 blocks
// part: B*NC rows of 2048 floats (h*16 + d*4 + e) = 4 MiB in d_ws.

__device__ __forceinline__ void fmadd4(float4& a, float s, const float4& b) {
  a.x += s * b.x; a.y += s * b.y; a.z += s * b.z; a.w += s * b.w;
}
__device__ __forceinline__ void add4(float4& a, const float4& b) {
  a.x += b.x; a.y += b.y; a.z += b.z; a.w += b.w;
}

__global__ __launch_bounds__(512, 4) void k_partial(const float* __restrict__ k,
                                                    const float* __restrict__ v,
                                                    float4* __restrict__ part) {
  const int bc  = blockIdx.x;          // b*NC + c
  const int b   = bc >> 7;
  const int c   = bc & (NC - 1);
  const int tid = threadIdx.x;
  const int sg  = tid >> 7;            // t-subchunk 0..3 (wave-uniform)
  const int h   = tid & 127;           // head (consecutive within wave)
  const int t0  = c * CT + sg * TSS;

  const size_t rb = ((size_t)b * T + t0) * (size_t)C + h * 4;
  const float* kp = k + rb;
  const float* vp = v + rb;

  float4 S0{0,0,0,0}, S1{0,0,0,0}, S2{0,0,0,0}, S3{0,0,0,0};
#pragma unroll
  for (int t = 0; t < TSS; ++t) {
    const float4 k4 = *reinterpret_cast<const float4*>(kp + (size_t)t * C);
    const float4 v4 = *reinterpret_cast<const float4*>(vp + (size_t)t * C);
    fmadd4(S0, k4.x, v4); fmadd4(S1, k4.y, v4);
    fmadd4(S2, k4.z, v4); fmadd4(S3, k4.w, v4);
  }

  __shared__ float4 lds[SG][4][H];     // 32 KiB
  lds[sg][0][h] = S0; lds[sg][1][h] = S1;
  lds[sg][2][h] = S2; lds[sg][3][h] = S3;
  __syncthreads();
  if (sg == 0) {
#pragma unroll
    for (int g = 1; g < SG; ++g) {
      add4(S0, lds[g][0][h]); add4(S1, lds[g][1][h]);
      add4(S2, lds[g][2][h]); add4(S3, lds[g][3][h]);
    }
    float4* pr = part + (size_t)bc * 512 + h * 4;
    pr[0] = S0; pr[1] = S1; pr[2] = S2; pr[3] = S3;
  }
}

// Parallel exclusive scan over the NC=128 chunks of each sequence.
// 128 blocks (b x 32 j-tiles) x 512 threads (8 c-groups x 64 j lanes).
__global__ __launch_bounds__(512, 4) void k_scan(float* __restrict__ part) {
  const int sb  = blockIdx.x >> 5;
  const int jt  = blockIdx.x & 31;
  const int tid = threadIdx.x;
  const int jl  = tid & 63;
  const int cg  = tid >> 6;            // wave-uniform
  const int j   = jt * 64 + jl;
  float* bp = part + (size_t)sb * NC * 2048 + j;
  const int c0 = cg * 16;
  float vals[16];
#pragma unroll
  for (int i = 0; i < 16; ++i) vals[i] = bp[(size_t)(c0 + i) * 2048];
  float sum = 0.f;
#pragma unroll
  for (int i = 0; i < 16; ++i) sum += vals[i];
  __shared__ float ls[8][64];
  ls[cg][jl] = sum;
  __syncthreads();
  float run = 0.f;
#pragma unroll
  for (int g = 0; g < 7; ++g)
    if (g < cg) run += ls[g][jl];
#pragma unroll
  for (int i = 0; i < 16; ++i) {
    bp[(size_t)(c0 + i) * 2048] = run;   // exclusive prefix
    run += vals[i];
  }
}

__global__ __launch_bounds__(512, 3) void k_out(const float* __restrict__ q,
                                                const float* __restrict__ k,
                                                const float* __restrict__ v,
                                                const float* __restrict__ emb,
                                                const float4* __restrict__ part,
                                                float* __restrict__ out) {
  const int bc  = blockIdx.x;
  const int b   = bc >> 7;
  const int c   = bc & (NC - 1);
  const int tid = threadIdx.x;
  const int sg  = tid >> 7;            // wave-uniform
  const int h   = tid & 127;
  const int t0  = c * CT + sg * TSS;

  // chunk-start prefix, loaded straight into the running state S
  const float4* pr = part + (size_t)bc * 512 + h * 4;
  float4 S0 = pr[0], S1 = pr[1], S2 = pr[2], S3 = pr[3];

  const size_t rb = ((size_t)b * T + t0) * (size_t)C + h * 4;
  const float* kp = k + rb;
  const float* vp = v + rb;
  const float* qp = q + rb;

  // ---- phase A: sub-chunk aggregate only (k,v read; ~32 live VGPR) ----
  float4 A0{0,0,0,0}, A1{0,0,0,0}, A2{0,0,0,0}, A3{0,0,0,0};
#pragma unroll
  for (int t = 0; t < TSS; ++t) {
    const float4 k4 = *reinterpret_cast<const float4*>(kp + (size_t)t * C);
    const float4 v4 = *reinterpret_cast<const float4*>(vp + (size_t)t * C);
    fmadd4(A0, k4.x, v4); fmadd4(A1, k4.y, v4);
    fmadd4(A2, k4.z, v4); fmadd4(A3, k4.w, v4);
  }

  // ---- exchange sub-chunk aggregates -> thread-start state S ----
  __shared__ float4 lds[SG][4][H];     // 32 KiB; 3 blocks/CU = 96 KiB ok
  lds[sg][0][h] = A0; lds[sg][1][h] = A1;
  lds[sg][2][h] = A2; lds[sg][3][h] = A3;
  __syncthreads();
#pragma unroll
  for (int g = 0; g < SG - 1; ++g) {
    if (g < sg) {                      // sg wave-uniform: no divergence
      add4(S0, lds[g][0][h]); add4(S1, lds[g][1][h]);
      add4(S2, lds[g][2][h]); add4(S3, lds[g][3][h]);
    }
  }

  // ---- replay: k,v re-read is XCD-L2-hit; q read once; o4 stores ----
  const float4 e4 = *reinterpret_cast<const float4*>(emb + h * 4);
  float* op = out + rb;
#pragma unroll
  for (int t = 0; t < TSS; ++t) {
    const float4 k4 = *reinterpret_cast<const float4*>(kp + (size_t)t * C);
    const float4 v4 = *reinterpret_cast<const float4*>(vp + (size_t)t * C);
    const float4 q4 = *reinterpret_cast<const float4*>(qp + (size_t)t * C);
    fmadd4(S0, k4.x, v4); fmadd4(S1, k4.y, v4);
    fmadd4(S2, k4.z, v4); fmadd4(S3, k4.w, v4);
    float4 o{0.f, 0.f, 0.f, 0.f};
    fmadd4(o, q4.x, S0); fmadd4(o, q4.y, S1);
    fmadd4(o, q4.z, S2); fmadd4(o, q4.w, S3);
    o.x *= e4.x; o.y *= e4.y; o.z *= e4.z; o.w *= e4.w;
    *reinterpret_cast<float4*>(op + (size_t)t * C) = o;
  }
}

extern "C" void kernel_launch(void* const* d_in, const int* in_sizes, int n_in,
                              void* d_out, int out_size, void* d_ws, size_t ws_size,
                              hipStream_t stream) {
  const float* xq  = (const float*)d_in[0];
  const float* xk  = (const float*)d_in[1];
  const float* xv  = (const float*)d_in[2];
  const float* emb = (const float*)d_in[3];
  float*  out  = (float*)d_out;
  float4* part = (float4*)d_ws;   // 4 MiB

  k_partial<<<NBLK, 512, 0, stream>>>(xk, xv, part);
  k_scan<<<B * 32, 512, 0, stream>>>((float*)d_ws);
  k_out<<<NBLK, 512, 0, stream>>>(xq, xk, xv, emb, part, out);
}